// Round 1
// baseline (281.104 us; speedup 1.0000x reference)
//
#include <hip/hip_runtime.h>

// Problem constants (from reference setup_inputs)
#define BB 2
#define CC 2
#define DD 160
#define HH 192
#define WW 224
#define DHW (DD * HH * WW)

#define VPT 4                      // voxels per thread (along w; 224 % 4 == 0)
#define TPB 256
#define NBX (DHW / (TPB * VPT))    // 6720 blocks per batch, exact
#define NXCD 8
#define CPX (NBX / NXCD)           // 840 (6720 % 8 == 0 -> bijective swizzle)

typedef float f2v __attribute__((ext_vector_type(2)));
typedef float f4v __attribute__((ext_vector_type(4)));

// 8-byte load at a 4-byte-aligned address (packed struct -> legal unaligned-capable lowering)
__device__ __forceinline__ f2v load2u(const float* p) {
    struct __attribute__((packed)) S { f2v v; };
    return ((const S*)p)->v;
}

__global__ __launch_bounds__(TPB) void affine_sample_kernel(
    const float* __restrict__ src,   // [B,C,D,H,W]
    const float* __restrict__ mat,   // [B,3,4]
    float* __restrict__ out)         // [B,C,D,H,W]
{
    // XCD-aware chunked swizzle: consecutive work -> same XCD L2
    int bx  = blockIdx.x;
    int sbx = (bx & (NXCD - 1)) * CPX + (bx >> 3);
    int base = (sbx * TPB + (int)threadIdx.x) * VPT;   // exact coverage, no guard
    int b = blockIdx.y;

    int w = base % WW;
    int t = base / WW;
    int h = t % HH;
    int d = t / HH;

    // theta = mat with translation column normalized per-row by (D,H,W)
    const float* m = mat + b * 12;   // uniform per block -> s_load
    float a00 = m[0], a01 = m[1], a02 = m[2],  a03 = m[3]  * (1.0f / (float)DD);
    float a10 = m[4], a11 = m[5], a12 = m[6],  a13 = m[7]  * (1.0f / (float)HH);
    float a20 = m[8], a21 = m[9], a22 = m[10], a23 = m[11] * (1.0f / (float)WW);

    float xn = -1.0f + (float)w * (2.0f / (float)(WW - 1));
    float yn = -1.0f + (float)h * (2.0f / (float)(HH - 1));
    float zn = -1.0f + (float)d * (2.0f / (float)(DD - 1));

    // sample coords (align_corners=True unnormalize folded in)
    float ix = (a00 * xn + a01 * yn + a02 * zn + a03 + 1.0f) * ((float)(WW - 1) * 0.5f);
    float iy = (a10 * xn + a11 * yn + a12 * zn + a13 + 1.0f) * ((float)(HH - 1) * 0.5f);
    float iz = (a20 * xn + a21 * yn + a22 * zn + a23 + 1.0f) * ((float)(DD - 1) * 0.5f);

    // per-w-step deltas in index space (map is affine in w)
    float dix = a00;
    float diy = a10 * ((float)(HH - 1) / (float)(WW - 1));
    float diz = a20 * ((float)(DD - 1) / (float)(WW - 1));

    const float* sb = src + (size_t)b * (CC * DHW);  // uniform base -> saddr loads

    f2v   P0[VPT][4], P1[VPT][4];      // gathered x-pairs, ch0 / ch1
    float q0a[VPT], q1a[VPT];          // clamp-folded x-pair weights
    float wzy0[VPT], wzy1[VPT], wzy2[VPT], wzy3[VPT];

    // ---- phase 1: addresses + weights + issue all 32 gathers ----
    #pragma unroll
    for (int v = 0; v < VPT; ++v) {
        float ixv = fmaf((float)v, dix, ix);
        float iyv = fmaf((float)v, diy, iy);
        float izv = fmaf((float)v, diz, iz);

        float fx0 = floorf(ixv), fy0 = floorf(iyv), fz0 = floorf(izv);
        float fx = ixv - fx0, fy = iyv - fy0, fz = izv - fz0;
        int x0 = (int)fx0, y0 = (int)fy0, z0 = (int)fz0;
        int x1 = x0 + 1, y1 = y0 + 1, z1 = z0 + 1;

        // 1-D weights with zero-padding validity folded in
        float wx0 = (x0 >= 0 && x0 < WW) ? (1.0f - fx) : 0.0f;
        float wx1 = (x1 >= 0 && x1 < WW) ? fx          : 0.0f;
        float wy0 = (y0 >= 0 && y0 < HH) ? (1.0f - fy) : 0.0f;
        float wy1 = (y1 >= 0 && y1 < HH) ? fy          : 0.0f;
        float wz0 = (z0 >= 0 && z0 < DD) ? (1.0f - fz) : 0.0f;
        float wz1 = (z1 >= 0 && z1 < DD) ? fz          : 0.0f;

        // clamped indices (safe loads); x-pair base covers both x corners
        int xc0 = min(max(x0, 0), WW - 1), xc1 = min(max(x1, 0), WW - 1);
        int yc0 = min(max(y0, 0), HH - 1), yc1 = min(max(y1, 0), HH - 1);
        int zc0 = min(max(z0, 0), DD - 1), zc1 = min(max(z1, 0), DD - 1);

        int xb   = min(xc0, WW - 2);   // in [0, WW-2]
        int sel0 = xc0 - xb;           // 0 or 1
        int sel1 = xc1 - xb;           // 0 or 1

        // fold clamp-selects into pair weights ONCE (replaces 16 per-row cndmasks)
        q0a[v] = (sel0 ? 0.0f : wx0) + (sel1 ? 0.0f : wx1);
        q1a[v] = (sel0 ? wx0 : 0.0f) + (sel1 ? wx1 : 0.0f);

        wzy0[v] = wz0 * wy0; wzy1[v] = wz0 * wy1;
        wzy2[v] = wz1 * wy0; wzy3[v] = wz1 * wy1;

        int zh0 = zc0 * HH, zh1 = zc1 * HH;
        int r0 = (zh0 + yc0) * WW + xb;
        int r1 = (zh0 + yc1) * WW + xb;
        int r2 = (zh1 + yc0) * WW + xb;
        int r3 = (zh1 + yc1) * WW + xb;

        P0[v][0] = load2u(sb + r0);
        P0[v][1] = load2u(sb + r1);
        P0[v][2] = load2u(sb + r2);
        P0[v][3] = load2u(sb + r3);
        P1[v][0] = load2u(sb + (DHW + r0));
        P1[v][1] = load2u(sb + (DHW + r1));
        P1[v][2] = load2u(sb + (DHW + r2));
        P1[v][3] = load2u(sb + (DHW + r3));
    }

    // ---- phase 2: interpolate (row weights shared across channels) ----
    f4v o0, o1;
    #pragma unroll
    for (int v = 0; v < VPT; ++v) {
        float rq00 = wzy0[v] * q0a[v], rq01 = wzy0[v] * q1a[v];
        float rq10 = wzy1[v] * q0a[v], rq11 = wzy1[v] * q1a[v];
        float rq20 = wzy2[v] * q0a[v], rq21 = wzy2[v] * q1a[v];
        float rq30 = wzy3[v] * q0a[v], rq31 = wzy3[v] * q1a[v];

        o0[v] = rq00 * P0[v][0][0] + rq01 * P0[v][0][1]
              + rq10 * P0[v][1][0] + rq11 * P0[v][1][1]
              + rq20 * P0[v][2][0] + rq21 * P0[v][2][1]
              + rq30 * P0[v][3][0] + rq31 * P0[v][3][1];
        o1[v] = rq00 * P1[v][0][0] + rq01 * P1[v][0][1]
              + rq10 * P1[v][1][0] + rq11 * P1[v][1][1]
              + rq20 * P1[v][2][0] + rq21 * P1[v][2][1]
              + rq30 * P1[v][3][0] + rq31 * P1[v][3][1];
    }

    float* ob = out + (size_t)b * (CC * DHW) + base;   // base % 4 == 0 -> 16B aligned
    __builtin_nontemporal_store(o0, (f4v*)ob);
    __builtin_nontemporal_store(o1, (f4v*)(ob + DHW));
}

extern "C" void kernel_launch(void* const* d_in, const int* in_sizes, int n_in,
                              void* d_out, int out_size, void* d_ws, size_t ws_size,
                              hipStream_t stream) {
    const float* src = (const float*)d_in[0];
    const float* mat = (const float*)d_in[1];
    float* out = (float*)d_out;

    dim3 block(TPB);
    dim3 grid(NBX, BB);
    affine_sample_kernel<<<grid, block, 0, stream>>>(src, mat, out);
}

// Round 2
// 243.745 us; speedup vs baseline: 1.1533x; 1.1533x over previous
//
#include <hip/hip_runtime.h>

// Problem constants (from reference setup_inputs)
#define BB 2
#define CC 2
#define DD 160
#define HH 192
#define WW 224
#define DHW (DD * HH * WW)

#define VPT 4                      // voxels per thread: one per z-quarter (160/4=40)
#define QD  (DD / VPT)             // 40 z-slices per quarter
#define QOFF (QD * HH * WW)        // voxel offset between quarters (= DHW/4)
#define TPB 256
#define NBX (QOFF / TPB)           // 6720 blocks per batch, exact
#define NXCD 8
#define CPX (NBX / NXCD)           // 840 (6720 % 8 == 0 -> bijective swizzle)

typedef float f2v __attribute__((ext_vector_type(2)));

// 8-byte load at a 4-byte-aligned address (packed struct -> legal unaligned-capable lowering)
__device__ __forceinline__ f2v load2u(const float* p) {
    struct __attribute__((packed)) S { f2v v; };
    return ((const S*)p)->v;
}

// launch_bounds(256, 4): 4 waves/EU floor -> VGPR budget 128, so the 32
// in-flight gather results (64 VGPRs) stay in registers instead of the
// compiler fusing load+consume at VGPR=40 (round-1 regression).
__global__ __launch_bounds__(TPB, 4) void affine_sample_kernel(
    const float* __restrict__ src,   // [B,C,D,H,W]
    const float* __restrict__ mat,   // [B,3,4]
    float* __restrict__ out)         // [B,C,D,H,W]
{
    // XCD-aware chunked swizzle: consecutive work -> same XCD L2
    int bx  = blockIdx.x;
    int sbx = (bx & (NXCD - 1)) * CPX + (bx >> 3);
    int base = sbx * TPB + (int)threadIdx.x;   // voxel id within quarter 0, [0, QOFF)
    int b = blockIdx.y;

    // one decomposition for all 4 voxels (they share w,h; d differs by QD)
    int w = base % WW;
    int t = base / WW;
    int h = t % HH;
    int d = t / HH;                            // in [0, QD)

    // theta = mat with translation column normalized per-row by (D,H,W)
    const float* m = mat + b * 12;             // uniform per block -> s_load
    float a00 = m[0], a01 = m[1], a02 = m[2],  a03 = m[3]  * (1.0f / (float)DD);
    float a10 = m[4], a11 = m[5], a12 = m[6],  a13 = m[7]  * (1.0f / (float)HH);
    float a20 = m[8], a21 = m[9], a22 = m[10], a23 = m[11] * (1.0f / (float)WW);

    float xn = -1.0f + (float)w * (2.0f / (float)(WW - 1));
    float yn = -1.0f + (float)h * (2.0f / (float)(HH - 1));
    float zn = -1.0f + (float)d * (2.0f / (float)(DD - 1));

    // sample coords for quarter 0 (align_corners=True unnormalize folded in)
    float ix = (a00 * xn + a01 * yn + a02 * zn + a03 + 1.0f) * ((float)(WW - 1) * 0.5f);
    float iy = (a10 * xn + a11 * yn + a12 * zn + a13 + 1.0f) * ((float)(HH - 1) * 0.5f);
    float iz = (a20 * xn + a21 * yn + a22 * zn + a23 + 1.0f) * ((float)(DD - 1) * 0.5f);

    // per-quarter deltas (z advances by QD slices; map is affine in z)
    float dzn = (float)QD * (2.0f / (float)(DD - 1));
    float dix = a02 * dzn * ((float)(WW - 1) * 0.5f);
    float diy = a12 * dzn * ((float)(HH - 1) * 0.5f);
    float diz = a22 * dzn * ((float)(DD - 1) * 0.5f);

    const float* s0 = src + (size_t)b * (CC * DHW);  // ch0 base (uniform -> saddr)
    const float* s1 = s0 + DHW;                       // ch1 base (uniform -> saddr)

    f2v   P0[VPT][4], P1[VPT][4];      // gathered x-pairs, ch0 / ch1
    float q0a[VPT], q1a[VPT];          // clamp-folded x-pair weights
    float wzy0[VPT], wzy1[VPT], wzy2[VPT], wzy3[VPT];

    // ---- phase 1: addresses + weights + issue all 32 gathers ----
    #pragma unroll
    for (int v = 0; v < VPT; ++v) {
        float ixv = fmaf((float)v, dix, ix);
        float iyv = fmaf((float)v, diy, iy);
        float izv = fmaf((float)v, diz, iz);

        float fx0 = floorf(ixv), fy0 = floorf(iyv), fz0 = floorf(izv);
        float fx = ixv - fx0, fy = iyv - fy0, fz = izv - fz0;
        int x0 = (int)fx0, y0 = (int)fy0, z0 = (int)fz0;
        int x1 = x0 + 1, y1 = y0 + 1, z1 = z0 + 1;

        // 1-D weights with zero-padding validity folded in
        float wx0 = (x0 >= 0 && x0 < WW) ? (1.0f - fx) : 0.0f;
        float wx1 = (x1 >= 0 && x1 < WW) ? fx          : 0.0f;
        float wy0 = (y0 >= 0 && y0 < HH) ? (1.0f - fy) : 0.0f;
        float wy1 = (y1 >= 0 && y1 < HH) ? fy          : 0.0f;
        float wz0 = (z0 >= 0 && z0 < DD) ? (1.0f - fz) : 0.0f;
        float wz1 = (z1 >= 0 && z1 < DD) ? fz          : 0.0f;

        // clamped indices (safe loads); x-pair base covers both x corners
        int xc0 = min(max(x0, 0), WW - 1), xc1 = min(max(x1, 0), WW - 1);
        int yc0 = min(max(y0, 0), HH - 1), yc1 = min(max(y1, 0), HH - 1);
        int zc0 = min(max(z0, 0), DD - 1), zc1 = min(max(z1, 0), DD - 1);

        int xb   = min(xc0, WW - 2);   // in [0, WW-2]
        int sel0 = xc0 - xb;           // 0 or 1
        int sel1 = xc1 - xb;           // 0 or 1

        // fold clamp-selects into pair weights once per voxel
        q0a[v] = (sel0 ? 0.0f : wx0) + (sel1 ? 0.0f : wx1);
        q1a[v] = (sel0 ? wx0 : 0.0f) + (sel1 ? wx1 : 0.0f);

        wzy0[v] = wz0 * wy0; wzy1[v] = wz0 * wy1;
        wzy2[v] = wz1 * wy0; wzy3[v] = wz1 * wy1;

        int zh0 = zc0 * HH, zh1 = zc1 * HH;
        int r0 = (zh0 + yc0) * WW + xb;
        int r1 = (zh0 + yc1) * WW + xb;
        int r2 = (zh1 + yc0) * WW + xb;
        int r3 = (zh1 + yc1) * WW + xb;

        P0[v][0] = load2u(s0 + r0);
        P0[v][1] = load2u(s0 + r1);
        P0[v][2] = load2u(s0 + r2);
        P0[v][3] = load2u(s0 + r3);
        P1[v][0] = load2u(s1 + r0);
        P1[v][1] = load2u(s1 + r1);
        P1[v][2] = load2u(s1 + r2);
        P1[v][3] = load2u(s1 + r3);
    }

    // keep all 32 loads issued before any consumption (no sink-to-use)
    __builtin_amdgcn_sched_barrier(0);

    // ---- phase 2: interpolate (row weights shared across channels) ----
    float* o = out + (size_t)b * (CC * DHW) + base;
    #pragma unroll
    for (int v = 0; v < VPT; ++v) {
        float rq00 = wzy0[v] * q0a[v], rq01 = wzy0[v] * q1a[v];
        float rq10 = wzy1[v] * q0a[v], rq11 = wzy1[v] * q1a[v];
        float rq20 = wzy2[v] * q0a[v], rq21 = wzy2[v] * q1a[v];
        float rq30 = wzy3[v] * q0a[v], rq31 = wzy3[v] * q1a[v];

        float acc0 = rq00 * P0[v][0][0] + rq01 * P0[v][0][1]
                   + rq10 * P0[v][1][0] + rq11 * P0[v][1][1]
                   + rq20 * P0[v][2][0] + rq21 * P0[v][2][1]
                   + rq30 * P0[v][3][0] + rq31 * P0[v][3][1];
        float acc1 = rq00 * P1[v][0][0] + rq01 * P1[v][0][1]
                   + rq10 * P1[v][1][0] + rq11 * P1[v][1][1]
                   + rq20 * P1[v][2][0] + rq21 * P1[v][2][1]
                   + rq30 * P1[v][3][0] + rq31 * P1[v][3][1];

        // lane-consecutive -> each store instr is 256B fully coalesced
        __builtin_nontemporal_store(acc0, o + v * QOFF);
        __builtin_nontemporal_store(acc1, o + (DHW + v * QOFF));
    }
}

extern "C" void kernel_launch(void* const* d_in, const int* in_sizes, int n_in,
                              void* d_out, int out_size, void* d_ws, size_t ws_size,
                              hipStream_t stream) {
    const float* src = (const float*)d_in[0];
    const float* mat = (const float*)d_in[1];
    float* out = (float*)d_out;

    dim3 block(TPB);
    dim3 grid(NBX, BB);
    affine_sample_kernel<<<grid, block, 0, stream>>>(src, mat, out);
}